// Round 12
// baseline (70.775 us; speedup 1.0000x reference)
//
#include <hip/hip_runtime.h>

// CategorySpecificLinear: out[t] = x[t] @ W[cid[t]] + bias[cid[t]]
// Pipeline (2 dispatches):
//   k_prep: block 0 = deterministic bucketize; [1,tpw] = W transpose->bf16;
//           next cvtb = x cvt->bf16; last zb = zero d_out (for atomic epilogue).
//   k_ggemm: BM=BN=128, BK=64, SPLIT-K=2, 1024 threads (16 waves 4x4),
//            depth-2 64KB LDS -> 2 blocks/CU, drain sync, atomicAdd epilogue.
//   Model: per-CU-iter time halves per doubling of independent blocks/CU
//   (R9 0.6us @4/CU, R8 0.9 @2/CU, R11 1.7 @1/CU); split-K gets 2/CU at the
//   minimal-bytes 128^2 tile. a+b exact-commutative => atomics deterministic.

typedef __attribute__((ext_vector_type(8))) short bf16x8;
typedef __attribute__((ext_vector_type(4))) float f32x4;
typedef __attribute__((ext_vector_type(8))) unsigned short ushort8_t;

__device__ __forceinline__ unsigned short f2bf(float f) {
  unsigned u = __float_as_uint(f);
  u += 0x7FFFu + ((u >> 16) & 1u);   // round-to-nearest-even
  return (unsigned short)(u >> 16);
}

// async global->LDS, 16B per lane; LDS dest = wave-uniform base + lane*16
__device__ __forceinline__ void gload_lds16(const unsigned short* g, unsigned short* l) {
  __builtin_amdgcn_global_load_lds(
      (const __attribute__((address_space(1))) unsigned int*)g,
      (__attribute__((address_space(3))) unsigned int*)l, 16, 0, 0);
}

#define MAXC 8

// ---- kernel 1: fused prep ----
__global__ void k_prep(const float* __restrict__ W, unsigned short* __restrict__ Wt,
                       int Dd, int Oo,
                       const float* __restrict__ x, unsigned short* __restrict__ xb, int nX,
                       const int* __restrict__ cid, int* __restrict__ counts,
                       int* __restrict__ bucket, int T, int C, int tpw, int cvtb,
                       float* __restrict__ outZ, int nOut) {
  int b   = blockIdx.x;
  int tid = threadIdx.x;

  if (b == 0) {
    // deterministic bucketize: per-thread counts -> per-category scan -> scatter
    __shared__ int cnt[256][MAXC];
    int tpt = (T + 255) / 256;
    int t0  = tid * tpt;
    int t1  = min(t0 + tpt, T);
    for (int c = 0; c < C; ++c) cnt[tid][c] = 0;
    for (int t = t0; t < t1; ++t) cnt[tid][cid[t]]++;
    __syncthreads();
    if (tid < C) {
      int run = 0;
      for (int t = 0; t < 256; ++t) { int v = cnt[t][tid]; cnt[t][tid] = run; run += v; }
      counts[tid] = run;
    }
    __syncthreads();
    for (int t = t0; t < t1; ++t) {
      int c = cid[t];
      int p = cnt[tid][c]++;
      bucket[c * T + p] = t;
    }
    return;
  }

  if (b > tpw + cvtb) {  // ---- zero-out role: 8 floats/thread ----
    int i = ((b - tpw - cvtb - 1) * 256 + tid) * 8;
    if (i >= nOut) return;
    float4 z = {0.f, 0.f, 0.f, 0.f};
    *reinterpret_cast<float4*>(outZ + i)     = z;
    *reinterpret_cast<float4*>(outZ + i + 4) = z;
    return;
  }

  if (b > tpw) {  // ---- cvt role: x fp32 -> bf16, 8/thread ----
    int i = ((b - tpw - 1) * 256 + tid) * 8;
    if (i >= nX) return;
    float4 a0 = *reinterpret_cast<const float4*>(x + i);
    float4 a1 = *reinterpret_cast<const float4*>(x + i + 4);
    ushort8_t o;
    o[0] = f2bf(a0.x); o[1] = f2bf(a0.y); o[2] = f2bf(a0.z); o[3] = f2bf(a0.w);
    o[4] = f2bf(a1.x); o[5] = f2bf(a1.y); o[6] = f2bf(a1.z); o[7] = f2bf(a1.w);
    *reinterpret_cast<ushort8_t*>(xb + i) = o;
    return;
  }

  // ---- transpose role: 64x64 tile of W[c] ----
  int bb  = b - 1;
  int tpc = (Dd / 64) * (Oo / 64);
  int c   = bb / tpc;
  int rem = bb % tpc;
  int d0  = (rem / (Oo / 64)) * 64;
  int o0  = (rem % (Oo / 64)) * 64;

  __shared__ float t[64][65];
  const float* Wc = W + (size_t)c * Dd * Oo;
#pragma unroll
  for (int p = 0; p < 4; ++p) {
    int chunk = p * 256 + tid;
    int r  = chunk >> 4;
    int cb = chunk & 15;
    float4 v = *reinterpret_cast<const float4*>(Wc + (size_t)(d0 + r) * Oo + o0 + cb * 4);
    t[r][cb * 4 + 0] = v.x; t[r][cb * 4 + 1] = v.y;
    t[r][cb * 4 + 2] = v.z; t[r][cb * 4 + 3] = v.w;
  }
  __syncthreads();
  unsigned short* Wtc = Wt + (size_t)c * Oo * Dd;
#pragma unroll
  for (int p = 0; p < 2; ++p) {
    int chunk = p * 256 + tid;
    int orow = chunk >> 3;
    int dseg = chunk & 7;
    ushort8_t w;
#pragma unroll
    for (int j = 0; j < 8; ++j) w[j] = f2bf(t[dseg * 8 + j][orow]);
    *reinterpret_cast<ushort8_t*>(Wtc + (size_t)(o0 + orow) * Dd + d0 + dseg * 8) = w;
  }
}

// ---- kernel 2: grouped GEMM, split-K=2 ----
#define BM 128
#define BN 128
#define BK 64
#define KSPLIT 2
#define TILE_A (BM * BK)   // 8192 elems = 16KB
#define TILE_B (BN * BK)   // 8192 elems = 16KB

__global__ __launch_bounds__(1024, 8) void k_ggemm(
    const unsigned short* __restrict__ xb, const unsigned short* __restrict__ Wt,
    const float* __restrict__ bias, const int* __restrict__ counts,
    const int* __restrict__ bucket, float* __restrict__ out,
    int T, int Dd, int Oo) {
  int c  = blockIdx.x;
  int Mc = counts[c];
  int kz = blockIdx.z & (KSPLIT - 1);
  int m0 = (blockIdx.z >> 1) * BM;
  if (m0 >= Mc) return;  // block-uniform exit
  int n0 = blockIdx.y * BN;

  __shared__ __align__(16) unsigned short Al[2][TILE_A];  // 32KB
  __shared__ __align__(16) unsigned short Bl[2][TILE_B];  // 32KB -> 64KB, 2 blk/CU

  const int tid  = threadIdx.x;
  const int lane = tid & 63;
  const int wid  = tid >> 6;                 // 0..15
  const int wm   = wid >> 2, wn = wid & 3;   // 4x4 waves, each 32x32 of C

  const int* buck = bucket + c * T;
  const unsigned short* Wc = Wt + (size_t)c * Oo * Dd;
  const int kbase = kz * (Dd / KSPLIT);      // this block's K-range start (elems)

  // staging: per wave 1 A-gload + 1 B-gload per tile; wave w covers rows
  // [w*8, w*8+8). Linear LDS dest; global source seg pre-swizzled
  // (seg = (lane&7) ^ (row&7)) so swizzled ds_read sees linear k. [rule 21]
  const unsigned short* aSrc;
  const unsigned short* bSrc;
  int sOff;  // wave-uniform LDS element offset (same for A and B)
  {
    int row = wid * 8 + (lane >> 3);
    int seg = (lane & 7) ^ (row & 7);
    int mr  = m0 + row;
    int tok = buck[mr < Mc ? mr : Mc - 1];  // clamp; masked at epilogue
    aSrc = xb + (size_t)tok * Dd + kbase + seg * 8;
    bSrc = Wc + (size_t)(n0 + row) * Dd + kbase + seg * 8;
    sOff = (wid * 8) * BK;
  }

  const f32x4 fzero = {0.f, 0.f, 0.f, 0.f};
  f32x4 acc[2][2];
#pragma unroll
  for (int i = 0; i < 2; ++i)
#pragma unroll
    for (int j = 0; j < 2; ++j) acc[i][j] = fzero;

  const int KT = Dd / BK / KSPLIT;  // 8

  // prologue: stage tile 0 into buf 0
  gload_lds16(aSrc, Al[0] + sOff);
  gload_lds16(bSrc, Bl[0] + sOff);
  asm volatile("s_waitcnt vmcnt(0)" ::: "memory");
  __builtin_amdgcn_sched_barrier(0);
  __builtin_amdgcn_s_barrier();

  for (int kt = 0; kt < KT; ++kt) {
    int cur = kt & 1;
    // issue tile kt+1 into other buffer (its readers done at last barrier)
    if (kt + 1 < KT) {
      int ko = (kt + 1) * BK;
      gload_lds16(aSrc + ko, Al[cur ^ 1] + sOff);
      gload_lds16(bSrc + ko, Bl[cur ^ 1] + sOff);
    }
    // compute tile kt (frag reads auto-waited via lgkmcnt before MFMA use)
#pragma unroll
    for (int kk = 0; kk < 2; ++kk) {
      bf16x8 af[2], bf[2];
#pragma unroll
      for (int mi = 0; mi < 2; ++mi) {
        int row  = wm * 32 + mi * 16 + (lane & 15);
        int slot = (kk * 4 + (lane >> 4)) ^ (row & 7);
        af[mi] = *reinterpret_cast<const bf16x8*>(&Al[cur][row * BK + slot * 8]);
      }
#pragma unroll
      for (int ni = 0; ni < 2; ++ni) {
        int row  = wn * 32 + ni * 16 + (lane & 15);
        int slot = (kk * 4 + (lane >> 4)) ^ (row & 7);
        bf[ni] = *reinterpret_cast<const bf16x8*>(&Bl[cur][row * BK + slot * 8]);
      }
#pragma unroll
      for (int mi = 0; mi < 2; ++mi)
#pragma unroll
        for (int ni = 0; ni < 2; ++ni)
          acc[mi][ni] = __builtin_amdgcn_mfma_f32_16x16x32_bf16(af[mi], bf[ni], acc[mi][ni], 0, 0, 0);
    }
    if (kt + 1 < KT) {
      asm volatile("s_waitcnt vmcnt(0)" ::: "memory");  // next tile landed
      __builtin_amdgcn_sched_barrier(0);
      __builtin_amdgcn_s_barrier();
    }
  }

  // epilogue: atomicAdd partial sums (out zeroed by k_prep). kz==0 adds bias.
  // Deterministic: 0+a=a and a+b=b+a are exact in IEEE fp32.
#pragma unroll
  for (int mi = 0; mi < 2; ++mi) {
    int rb = m0 + wm * 32 + mi * 16 + (lane >> 4) * 4;
#pragma unroll
    for (int r = 0; r < 4; ++r) {
      int mrow = rb + r;
      if (mrow < Mc) {
        int tok = buck[mrow];
        float* orow = out + (size_t)tok * Oo;
#pragma unroll
        for (int ni = 0; ni < 2; ++ni) {
          int col = n0 + wn * 32 + ni * 16 + (lane & 15);
          float v = acc[mi][ni][r] + (kz == 0 ? bias[c * Oo + col] : 0.f);
          atomicAdd(&orow[col], v);
        }
      }
    }
  }
}

extern "C" void kernel_launch(void* const* d_in, const int* in_sizes, int n_in,
                              void* d_out, int out_size, void* d_ws, size_t ws_size,
                              hipStream_t stream) {
  const float* x    = (const float*)d_in[0];
  const int*   cid  = (const int*)d_in[1];
  const float* W    = (const float*)d_in[2];
  const float* bias = (const float*)d_in[3];
  float* out = (float*)d_out;

  int T = in_sizes[1];            // 4096
  int D = in_sizes[0] / T;        // 1024
  int O = out_size / T;           // 1024
  int C = in_sizes[3] / O;        // 8

  char* ws = (char*)d_ws;
  int* counts = (int*)ws;                                   // C ints
  int* bucket = (int*)(ws + 64);                            // C*T ints
  unsigned short* xb = (unsigned short*)(ws + 64 + (size_t)C * T * 4);  // T*D bf16
  unsigned short* Wt = xb + (size_t)T * D;                  // C*O*D bf16

  int tpw  = C * (D / 64) * (O / 64);            // 2048 transpose blocks
  int cvtb = (T * D / 8 + 255) / 256;            // 2048 cvt blocks
  int zb   = (out_size / 8 + 255) / 256;         // 2048 zero-out blocks
  k_prep<<<1 + tpw + cvtb + zb, 256, 0, stream>>>(W, Wt, D, O, x, xb, T * D,
                                                  cid, counts, bucket, T, C, tpw, cvtb,
                                                  out, out_size);
  k_ggemm<<<dim3(C, O / BN, KSPLIT * ((T + BM - 1) / BM)), 1024, 0, stream>>>(
      xb, Wt, bias, counts, bucket, out, T, D, O);
}

// Round 13
// 65.468 us; speedup vs baseline: 1.0811x; 1.0811x over previous
//
#include <hip/hip_runtime.h>

// CategorySpecificLinear: out[t] = x[t] @ W[cid[t]] + bias[cid[t]]
// Pipeline (2 dispatches):
//   k_prep: block 0 = deterministic bucketize; [1,tpw] = W transpose->bf16;
//           next cvtb = x cvt->bf16; last zb = zero d_out (atomic epilogue).
//   k_ggemm: BM=BN=128, BK=32, SPLIT-K=2, 512 threads (8 waves 4x2),
//            depth-3 counted vmcnt(2), 48KB LDS -> 2 blk/CU, atomicAdd epilogue.
//   Law (R8/R9/R11/R12): staging rate is set by block size (512>1024) and
//   sync (d3-counted>drain); bytes minimized at 128^2. This is the best corner.

typedef __attribute__((ext_vector_type(8))) short bf16x8;
typedef __attribute__((ext_vector_type(4))) float f32x4;
typedef __attribute__((ext_vector_type(8))) unsigned short ushort8_t;

__device__ __forceinline__ unsigned short f2bf(float f) {
  unsigned u = __float_as_uint(f);
  u += 0x7FFFu + ((u >> 16) & 1u);   // round-to-nearest-even
  return (unsigned short)(u >> 16);
}

// async global->LDS, 16B per lane; LDS dest = wave-uniform base + lane*16
__device__ __forceinline__ void gload_lds16(const unsigned short* g, unsigned short* l) {
  __builtin_amdgcn_global_load_lds(
      (const __attribute__((address_space(1))) unsigned int*)g,
      (__attribute__((address_space(3))) unsigned int*)l, 16, 0, 0);
}

#define MAXC 8

// ---- kernel 1: fused prep (unchanged from R12) ----
__global__ void k_prep(const float* __restrict__ W, unsigned short* __restrict__ Wt,
                       int Dd, int Oo,
                       const float* __restrict__ x, unsigned short* __restrict__ xb, int nX,
                       const int* __restrict__ cid, int* __restrict__ counts,
                       int* __restrict__ bucket, int T, int C, int tpw, int cvtb,
                       float* __restrict__ outZ, int nOut) {
  int b   = blockIdx.x;
  int tid = threadIdx.x;

  if (b == 0) {
    __shared__ int cnt[256][MAXC];
    int tpt = (T + 255) / 256;
    int t0  = tid * tpt;
    int t1  = min(t0 + tpt, T);
    for (int c = 0; c < C; ++c) cnt[tid][c] = 0;
    for (int t = t0; t < t1; ++t) cnt[tid][cid[t]]++;
    __syncthreads();
    if (tid < C) {
      int run = 0;
      for (int t = 0; t < 256; ++t) { int v = cnt[t][tid]; cnt[t][tid] = run; run += v; }
      counts[tid] = run;
    }
    __syncthreads();
    for (int t = t0; t < t1; ++t) {
      int c = cid[t];
      int p = cnt[tid][c]++;
      bucket[c * T + p] = t;
    }
    return;
  }

  if (b > tpw + cvtb) {  // zero-out role
    int i = ((b - tpw - cvtb - 1) * 256 + tid) * 8;
    if (i >= nOut) return;
    float4 z = {0.f, 0.f, 0.f, 0.f};
    *reinterpret_cast<float4*>(outZ + i)     = z;
    *reinterpret_cast<float4*>(outZ + i + 4) = z;
    return;
  }

  if (b > tpw) {  // cvt role
    int i = ((b - tpw - 1) * 256 + tid) * 8;
    if (i >= nX) return;
    float4 a0 = *reinterpret_cast<const float4*>(x + i);
    float4 a1 = *reinterpret_cast<const float4*>(x + i + 4);
    ushort8_t o;
    o[0] = f2bf(a0.x); o[1] = f2bf(a0.y); o[2] = f2bf(a0.z); o[3] = f2bf(a0.w);
    o[4] = f2bf(a1.x); o[5] = f2bf(a1.y); o[6] = f2bf(a1.z); o[7] = f2bf(a1.w);
    *reinterpret_cast<ushort8_t*>(xb + i) = o;
    return;
  }

  // transpose role
  int bb  = b - 1;
  int tpc = (Dd / 64) * (Oo / 64);
  int c   = bb / tpc;
  int rem = bb % tpc;
  int d0  = (rem / (Oo / 64)) * 64;
  int o0  = (rem % (Oo / 64)) * 64;

  __shared__ float t[64][65];
  const float* Wc = W + (size_t)c * Dd * Oo;
#pragma unroll
  for (int p = 0; p < 4; ++p) {
    int chunk = p * 256 + tid;
    int r  = chunk >> 4;
    int cb = chunk & 15;
    float4 v = *reinterpret_cast<const float4*>(Wc + (size_t)(d0 + r) * Oo + o0 + cb * 4);
    t[r][cb * 4 + 0] = v.x; t[r][cb * 4 + 1] = v.y;
    t[r][cb * 4 + 2] = v.z; t[r][cb * 4 + 3] = v.w;
  }
  __syncthreads();
  unsigned short* Wtc = Wt + (size_t)c * Oo * Dd;
#pragma unroll
  for (int p = 0; p < 2; ++p) {
    int chunk = p * 256 + tid;
    int orow = chunk >> 3;
    int dseg = chunk & 7;
    ushort8_t w;
#pragma unroll
    for (int j = 0; j < 8; ++j) w[j] = f2bf(t[dseg * 8 + j][orow]);
    *reinterpret_cast<ushort8_t*>(Wtc + (size_t)(o0 + orow) * Dd + d0 + dseg * 8) = w;
  }
}

// ---- kernel 2: grouped GEMM, split-K=2, BK=32, depth-3 counted ----
#define BM 128
#define BN 128
#define BK 32
#define KSPLIT 2
#define TILE_A (BM * BK)   // 4096 elems = 8KB
#define TILE_B (BN * BK)   // 4096 elems = 8KB

__global__ __launch_bounds__(512) void k_ggemm(
    const unsigned short* __restrict__ xb, const unsigned short* __restrict__ Wt,
    const float* __restrict__ bias, const int* __restrict__ counts,
    const int* __restrict__ bucket, float* __restrict__ out,
    int T, int Dd, int Oo) {
  int c  = blockIdx.x;
  int Mc = counts[c];
  int kz = blockIdx.z & (KSPLIT - 1);
  int m0 = (blockIdx.z >> 1) * BM;
  if (m0 >= Mc) return;  // block-uniform exit
  int n0 = blockIdx.y * BN;

  __shared__ __align__(16) unsigned short Al[3][TILE_A];  // 24KB
  __shared__ __align__(16) unsigned short Bl[3][TILE_B];  // 24KB -> 48KB, 2 blk/CU

  const int tid  = threadIdx.x;
  const int lane = tid & 63;
  const int wid  = tid >> 6;                 // 0..7
  const int wm   = wid >> 1, wn = wid & 1;   // 4x2 waves, each 32x64 of C

  const int* buck = bucket + c * T;
  const unsigned short* Wc = Wt + (size_t)c * Oo * Dd;
  const int kbase = kz * (Dd / KSPLIT);

  // staging (BK=32, rows are 64B = 4 x 16B chunks): wave w stages A rows
  // [w*16,+16) and B rows [w*16,+16); lane -> (row = w*16 + lane>>2,
  // chunk = lane&3). Linear LDS dest; source chunk pre-swizzled with
  // f(row) = (row>>1)&3 (derived conflict-free: 2 lanes/16B-col on frag read).
  const unsigned short* aSrc;
  const unsigned short* bSrc;
  int sOff;  // wave-uniform LDS element offset (same for A and B)
  {
    int row = wid * 16 + (lane >> 2);
    int seg = (lane & 3) ^ ((row >> 1) & 3);
    int mr  = m0 + row;
    int tok = buck[mr < Mc ? mr : Mc - 1];  // clamp; masked at epilogue
    aSrc = xb + (size_t)tok * Dd + kbase + seg * 8;
    bSrc = Wc + (size_t)(n0 + row) * Dd + kbase + seg * 8;
    sOff = (wid * 16) * BK;
  }

  const f32x4 fzero = {0.f, 0.f, 0.f, 0.f};
  f32x4 acc[2][4];
#pragma unroll
  for (int i = 0; i < 2; ++i)
#pragma unroll
    for (int j = 0; j < 4; ++j) acc[i][j] = fzero;

  const int KT = Dd / BK / KSPLIT;  // 16

  // prologue: issue tiles 0 and 1 (2 gloads each per wave)
#pragma unroll
  for (int t8 = 0; t8 < 2; ++t8) {
    int ko = t8 * BK;
    gload_lds16(aSrc + ko, Al[t8] + sOff);
    gload_lds16(bSrc + ko, Bl[t8] + sOff);
  }

  int cur = 0;
  for (int kt = 0; kt < KT; ++kt) {
    // my prev frag ds_reads drained; tile kt's 2 loads landed
    // (2 newer = tile kt+1's may stay in flight across the barrier)
    asm volatile("s_waitcnt lgkmcnt(0)" ::: "memory");
    if (kt < KT - 1) {
      asm volatile("s_waitcnt vmcnt(2)" ::: "memory");
    } else {
      asm volatile("s_waitcnt vmcnt(0)" ::: "memory");
    }
    __builtin_amdgcn_sched_barrier(0);
    __builtin_amdgcn_s_barrier();
    __builtin_amdgcn_sched_barrier(0);

    if (kt + 2 < KT) {
      int nb = cur + 2; if (nb >= 3) nb -= 3;
      int ko = (kt + 2) * BK;
      gload_lds16(aSrc + ko, Al[nb] + sOff);
      gload_lds16(bSrc + ko, Bl[nb] + sOff);
    }

    // compute tile kt: frag slot = (lane>>4) ^ ((row>>1)&3)
    {
      bf16x8 af[2], bf[4];
#pragma unroll
      for (int mi = 0; mi < 2; ++mi) {
        int row  = wm * 32 + mi * 16 + (lane & 15);
        int slot = (lane >> 4) ^ ((row >> 1) & 3);
        af[mi] = *reinterpret_cast<const bf16x8*>(&Al[cur][row * BK + slot * 8]);
      }
#pragma unroll
      for (int ni = 0; ni < 4; ++ni) {
        int row  = wn * 64 + ni * 16 + (lane & 15);
        int slot = (lane >> 4) ^ ((row >> 1) & 3);
        bf[ni] = *reinterpret_cast<const bf16x8*>(&Bl[cur][row * BK + slot * 8]);
      }
#pragma unroll
      for (int mi = 0; mi < 2; ++mi)
#pragma unroll
        for (int ni = 0; ni < 4; ++ni)
          acc[mi][ni] = __builtin_amdgcn_mfma_f32_16x16x32_bf16(af[mi], bf[ni], acc[mi][ni], 0, 0, 0);
    }
    cur = (cur + 1 == 3) ? 0 : cur + 1;
  }

  // epilogue: atomicAdd partials (out zeroed in k_prep); kz==0 adds bias.
  // Deterministic: 0+a and a+b are exact/commutative in IEEE fp32.
#pragma unroll
  for (int mi = 0; mi < 2; ++mi) {
    int rb = m0 + wm * 32 + mi * 16 + (lane >> 4) * 4;
#pragma unroll
    for (int r = 0; r < 4; ++r) {
      int mrow = rb + r;
      if (mrow < Mc) {
        int tok = buck[mrow];
        float* orow = out + (size_t)tok * Oo;
#pragma unroll
        for (int ni = 0; ni < 4; ++ni) {
          int col = n0 + wn * 64 + ni * 16 + (lane & 15);
          float v = acc[mi][ni][r] + (kz == 0 ? bias[c * Oo + col] : 0.f);
          atomicAdd(&orow[col], v);
        }
      }
    }
  }
}

extern "C" void kernel_launch(void* const* d_in, const int* in_sizes, int n_in,
                              void* d_out, int out_size, void* d_ws, size_t ws_size,
                              hipStream_t stream) {
  const float* x    = (const float*)d_in[0];
  const int*   cid  = (const int*)d_in[1];
  const float* W    = (const float*)d_in[2];
  const float* bias = (const float*)d_in[3];
  float* out = (float*)d_out;

  int T = in_sizes[1];            // 4096
  int D = in_sizes[0] / T;        // 1024
  int O = out_size / T;           // 1024
  int C = in_sizes[3] / O;        // 8

  char* ws = (char*)d_ws;
  int* counts = (int*)ws;                                   // C ints
  int* bucket = (int*)(ws + 64);                            // C*T ints
  unsigned short* xb = (unsigned short*)(ws + 64 + (size_t)C * T * 4);  // T*D bf16
  unsigned short* Wt = xb + (size_t)T * D;                  // C*O*D bf16

  int tpw  = C * (D / 64) * (O / 64);            // 2048 transpose blocks
  int cvtb = (T * D / 8 + 255) / 256;            // 2048 cvt blocks
  int zb   = (out_size / 8 + 255) / 256;         // 2048 zero-out blocks
  k_prep<<<1 + tpw + cvtb + zb, 256, 0, stream>>>(W, Wt, D, O, x, xb, T * D,
                                                  cid, counts, bucket, T, C, tpw, cvtb,
                                                  out, out_size);
  k_ggemm<<<dim3(C, O / BN, KSPLIT * ((T + BM - 1) / BM)), 512, 0, stream>>>(
      xb, Wt, bias, counts, bucket, out, T, D, O);
}